// Round 1
// baseline (989.791 us; speedup 1.0000x reference)
//
#include <hip/hip_runtime.h>
#include <cstdint>
#include <cstddef>

#define NF 128          // lap feature width (IN_F == HID_F == 128)
#define SCAN_B 256

// ---------------- degree / CSR build ----------------

static __global__ void k_count(const int* __restrict__ dst, int ne, int* __restrict__ counts) {
    int e = blockIdx.x * blockDim.x + threadIdx.x;
    if (e < ne) atomicAdd(&counts[dst[e]], 1);
}

static __global__ void k_dinv(const int* __restrict__ counts, int n, float* __restrict__ dinv) {
    int i = blockIdx.x * blockDim.x + threadIdx.x;
    if (i < n) {
        float d = (float)counts[i];
        d = fmaxf(d, 1.0f);
        dinv[i] = rsqrtf(d);
    }
}

static __global__ void k_scan1(const int* __restrict__ counts, int n,
                               int* __restrict__ row_off, int* __restrict__ bsum) {
    __shared__ int s[SCAN_B];
    int t = threadIdx.x;
    int base = blockIdx.x * SCAN_B;
    int v = (base + t < n) ? counts[base + t] : 0;
    s[t] = v;
    __syncthreads();
    for (int off = 1; off < SCAN_B; off <<= 1) {
        int x = 0;
        if (t >= off) x = s[t - off];
        __syncthreads();
        if (t >= off) s[t] += x;
        __syncthreads();
    }
    if (base + t < n) row_off[base + t] = s[t] - v;  // block-local exclusive
    if (t == SCAN_B - 1) bsum[blockIdx.x] = s[t];
}

static __global__ void k_scan2(int* __restrict__ bsum, int nb) {
    __shared__ int s[512];
    int t = threadIdx.x;
    int v = (t < nb) ? bsum[t] : 0;
    s[t] = v;
    __syncthreads();
    for (int off = 1; off < 512; off <<= 1) {
        int x = 0;
        if (t >= off) x = s[t - off];
        __syncthreads();
        if (t >= off) s[t] += x;
        __syncthreads();
    }
    if (t < nb) bsum[t] = s[t] - v;  // exclusive block offsets
}

static __global__ void k_scan3(int* __restrict__ row_off, const int* __restrict__ bsum,
                               int n, int ne) {
    int i = blockIdx.x * SCAN_B + threadIdx.x;
    if (i < n) row_off[i] += bsum[blockIdx.x];
    if (i == 0) row_off[n] = ne;
}

static __global__ void k_copy_i32(const int* __restrict__ a, int* __restrict__ b, int n) {
    int i = blockIdx.x * blockDim.x + threadIdx.x;
    if (i < n) b[i] = a[i];
}

static __global__ void k_fill(const int* __restrict__ src, const int* __restrict__ dst, int ne,
                              int* __restrict__ cursor, int* __restrict__ csr) {
    int e = blockIdx.x * blockDim.x + threadIdx.x;
    if (e < ne) {
        int d = dst[e];
        int p = atomicAdd(&cursor[d], 1);
        csr[p] = src[e];
    }
}

// ---------------- Laplacian gather: out = a*(agg*dinv) + b*Xin + c*Xo ----------------
// agg[i] = sum over incoming edges (src s) of Xin[s]*dinv[s]

static __global__ __launch_bounds__(NF) void k_lap(
    const float* __restrict__ Xin, const float* __restrict__ Xo,
    const int* __restrict__ row_off, const int* __restrict__ csr,
    const float* __restrict__ dinv,
    float a, float b, float c,
    float* __restrict__ out, int n) {
    int i = blockIdx.x;
    int t = threadIdx.x;
    int e0 = row_off[i], e1 = row_off[i + 1];
    float acc = 0.f;
    for (int e = e0; e < e1; ++e) {
        int s = csr[e];
        acc += Xin[(size_t)s * NF + t] * dinv[s];
    }
    size_t idx = (size_t)i * NF + t;
    float r = a * (acc * dinv[i]) + b * Xin[idx];
    if (Xo) r += c * Xo[idx];
    out[idx] = r;
}

// ---------------- generic fp32 GEMM: out[M][N] = concat(X0..X2)[M][Ktot] @ W[N][Ktot]^T ----
// mode 0: y+bias   1: relu(y+bias)   2: bn(relu(y+bias))   3: relu(y+bias)+res

#define BM 64
#define BN 64
#define BK 32

static __global__ __launch_bounds__(256) void k_gemm(
    const float* __restrict__ X0, const float* __restrict__ X1, const float* __restrict__ X2,
    int Kseg, int nseg,
    const float* __restrict__ W, const float* __restrict__ bias,
    const float* __restrict__ res,
    const float* __restrict__ bng, const float* __restrict__ bnb,
    const float* __restrict__ bnm, const float* __restrict__ bnv,
    int M, int N, int mode, float* __restrict__ out) {
    __shared__ float Xs[BM][BK + 1];
    __shared__ float Ws[BN][BK + 1];
    const int t = threadIdx.x;
    const int m0 = blockIdx.x * BM;
    const int n0 = blockIdx.y * BN;
    const int tm = t >> 4;   // 0..15
    const int tn = t & 15;   // 0..15
    float acc[4][4] = {{0.f}};
    const int Ktot = Kseg * nseg;
    const float* segs[3] = {X0, X1, X2};

    for (int kt = 0; kt < Ktot; kt += BK) {
        const float* Xp = segs[kt / Kseg];
        const int klocal = kt % Kseg;
        // stage X tile: BM x BK (2048 floats, 2x float4/thread)
#pragma unroll
        for (int it = 0; it < 2; ++it) {
            int idx = it * 256 + t;     // 0..511
            int row = idx >> 3;         // 0..63
            int kq  = idx & 7;          // 0..7 (float4 per row)
            int gm = m0 + row;
            float4 v = make_float4(0.f, 0.f, 0.f, 0.f);
            if (gm < M) v = *(const float4*)&Xp[(size_t)gm * Kseg + klocal + kq * 4];
            Xs[row][kq * 4 + 0] = v.x;
            Xs[row][kq * 4 + 1] = v.y;
            Xs[row][kq * 4 + 2] = v.z;
            Xs[row][kq * 4 + 3] = v.w;
        }
        // stage W tile: BN x BK
#pragma unroll
        for (int it = 0; it < 2; ++it) {
            int idx = it * 256 + t;
            int row = idx >> 3;
            int kq  = idx & 7;
            int gn = n0 + row;  // N is a multiple of BN
            float4 v = *(const float4*)&W[(size_t)gn * Ktot + kt + kq * 4];
            Ws[row][kq * 4 + 0] = v.x;
            Ws[row][kq * 4 + 1] = v.y;
            Ws[row][kq * 4 + 2] = v.z;
            Ws[row][kq * 4 + 3] = v.w;
        }
        __syncthreads();
#pragma unroll
        for (int k = 0; k < BK; ++k) {
            float av[4], bv[4];
#pragma unroll
            for (int i = 0; i < 4; ++i) av[i] = Xs[tm * 4 + i][k];
#pragma unroll
            for (int j = 0; j < 4; ++j) bv[j] = Ws[tn * 4 + j][k];
#pragma unroll
            for (int i = 0; i < 4; ++i)
#pragma unroll
                for (int j = 0; j < 4; ++j) acc[i][j] += av[i] * bv[j];
        }
        __syncthreads();
    }

#pragma unroll
    for (int i = 0; i < 4; ++i) {
        int gm = m0 + tm * 4 + i;
        if (gm >= M) continue;
#pragma unroll
        for (int j = 0; j < 4; ++j) {
            int gn = n0 + tn * 4 + j;
            float y = acc[i][j] + bias[gn];
            if (mode >= 1) y = fmaxf(y, 0.f);
            if (mode == 2) {
                float sc = rsqrtf(bnv[gn] + 1e-5f) * bng[gn];
                y = (y - bnm[gn]) * sc + bnb[gn];
            }
            if (mode == 3) y += res[(size_t)gm * N + gn];
            out[(size_t)gm * N + gn] = y;
        }
    }
}

// ---------------- launch ----------------

extern "C" void kernel_launch(void* const* d_in, const int* in_sizes, int n_in,
                              void* d_out, int out_size, void* d_ws, size_t ws_size,
                              hipStream_t stream) {
    const float* features = (const float*)d_in[0];
    const int*   esrc     = (const int*)d_in[1];
    const int*   edst     = (const int*)d_in[2];
    const float* W1   = (const float*)d_in[3];
    const float* b1   = (const float*)d_in[4];
    const float* bng  = (const float*)d_in[5];
    const float* bnb  = (const float*)d_in[6];
    const float* bnm  = (const float*)d_in[7];
    const float* bnv  = (const float*)d_in[8];
    const float* W3   = (const float*)d_in[9];
    const float* b3   = (const float*)d_in[10];
    const float* Wm1  = (const float*)d_in[11];
    const float* bm1  = (const float*)d_in[12];
    const float* Wm2  = (const float*)d_in[13];
    const float* bm2  = (const float*)d_in[14];
    float* out = (float*)d_out;

    const int n  = in_sizes[0] / NF;     // 100000
    const int ne = in_sizes[1];          // 600000
    const int OUTF = out_size / n;       // 64

    // workspace carve-up (256B aligned)
    uint8_t* w = (uint8_t*)d_ws;
    size_t off = 0;
    auto alloc = [&](size_t bytes) -> void* {
        void* p = w + off;
        off = (off + bytes + 255) & ~(size_t)255;
        return p;
    };
    float* dinv   = (float*)alloc((size_t)n * 4);
    int* counts   = (int*)alloc((size_t)n * 4);
    int* row_off  = (int*)alloc(((size_t)n + 1) * 4);
    int* cursor   = (int*)alloc((size_t)n * 4);
    int* csr      = (int*)alloc((size_t)ne * 4);
    int* bsum     = (int*)alloc(4096);
    float* bufB   = (float*)alloc((size_t)n * NF * 4);  // X1
    float* bufC   = (float*)alloc((size_t)n * NF * 4);  // X2
    float* bufD   = (float*)alloc((size_t)n * NF * 4);  // h1 (conv1 out, residual)
    float* bufE   = (float*)alloc((size_t)n * NF * 4);  // conv2 out
    (void)ws_size;

    const int TB = 256;
    const int nbE = (ne + TB - 1) / TB;
    const int nbN = (n + TB - 1) / TB;

    // degree + dinv + CSR
    hipMemsetAsync(counts, 0, (size_t)n * 4, stream);
    k_count<<<nbE, TB, 0, stream>>>(edst, ne, counts);
    k_dinv<<<nbN, TB, 0, stream>>>(counts, n, dinv);
    k_scan1<<<nbN, SCAN_B, 0, stream>>>(counts, n, row_off, bsum);
    k_scan2<<<1, 512, 0, stream>>>(bsum, nbN);
    k_scan3<<<nbN, SCAN_B, 0, stream>>>(row_off, bsum, n, ne);
    k_copy_i32<<<nbN, TB, 0, stream>>>(row_off, cursor, n);
    k_fill<<<nbE, TB, 0, stream>>>(esrc, edst, ne, cursor, csr);

    // ---- conv1 on features ----
    // X1 = agg(X0)*dinv - X0
    k_lap<<<n, NF, 0, stream>>>(features, nullptr, row_off, csr, dinv, 1.f, -1.f, 0.f, bufB, n);
    // X2 = 2*agg(X1)*dinv - 2*X1 - X0
    k_lap<<<n, NF, 0, stream>>>(bufB, features, row_off, csr, dinv, 2.f, -2.f, -1.f, bufC, n);
    {   // h1 = bn(relu([X0|X1|X2] @ W1^T + b1))
        dim3 g((n + BM - 1) / BM, NF / BN);
        k_gemm<<<g, 256, 0, stream>>>(features, bufB, bufC, NF, 3, W1, b1,
                                      nullptr, bng, bnb, bnm, bnv, n, NF, 2, bufD);
    }

    // ---- conv2 on h1 ----
    k_lap<<<n, NF, 0, stream>>>(bufD, nullptr, row_off, csr, dinv, 1.f, -1.f, 0.f, bufB, n);
    k_lap<<<n, NF, 0, stream>>>(bufB, bufD, row_off, csr, dinv, 2.f, -2.f, -1.f, bufC, n);
    {   // x = relu([h1|X1|X2] @ W3^T + b3) + h1
        dim3 g((n + BM - 1) / BM, NF / BN);
        k_gemm<<<g, 256, 0, stream>>>(bufD, bufB, bufC, NF, 3, W3, b3,
                                      bufD, nullptr, nullptr, nullptr, nullptr, n, NF, 3, bufE);
    }

    // ---- MLP ----
    {   // h = relu(x @ Wm1^T + bm1)
        dim3 g((n + BM - 1) / BM, NF / BN);
        k_gemm<<<g, 256, 0, stream>>>(bufE, nullptr, nullptr, NF, 1, Wm1, bm1,
                                      nullptr, nullptr, nullptr, nullptr, nullptr, n, NF, 1, bufB);
    }
    {   // out = h @ Wm2^T + bm2
        dim3 g((n + BM - 1) / BM, OUTF / BN);
        k_gemm<<<g, 256, 0, stream>>>(bufB, nullptr, nullptr, NF, 1, Wm2, bm2,
                                      nullptr, nullptr, nullptr, nullptr, nullptr, n, OUTF, 0, out);
    }
}

// Round 2
// 679.843 us; speedup vs baseline: 1.4559x; 1.4559x over previous
//
#include <hip/hip_runtime.h>
#include <cstdint>
#include <cstddef>

#define NF 128          // lap feature width (IN_F == HID_F == 128)
#define SCAN_B 256

typedef __attribute__((ext_vector_type(4))) float f32x4;
typedef __attribute__((ext_vector_type(8))) short bf16x8;
typedef __attribute__((ext_vector_type(4))) short s16x4;

// ---------------- degree / CSR build ----------------

static __global__ void k_count(const int* __restrict__ dst, int ne, int* __restrict__ counts) {
    int e = blockIdx.x * blockDim.x + threadIdx.x;
    if (e < ne) atomicAdd(&counts[dst[e]], 1);
}

static __global__ void k_dinv(const int* __restrict__ counts, int n, float* __restrict__ dinv) {
    int i = blockIdx.x * blockDim.x + threadIdx.x;
    if (i < n) {
        float d = (float)counts[i];
        d = fmaxf(d, 1.0f);
        dinv[i] = rsqrtf(d);
    }
}

static __global__ void k_scan1(const int* __restrict__ counts, int n,
                               int* __restrict__ row_off, int* __restrict__ bsum) {
    __shared__ int s[SCAN_B];
    int t = threadIdx.x;
    int base = blockIdx.x * SCAN_B;
    int v = (base + t < n) ? counts[base + t] : 0;
    s[t] = v;
    __syncthreads();
    for (int off = 1; off < SCAN_B; off <<= 1) {
        int x = 0;
        if (t >= off) x = s[t - off];
        __syncthreads();
        if (t >= off) s[t] += x;
        __syncthreads();
    }
    if (base + t < n) row_off[base + t] = s[t] - v;  // block-local exclusive
    if (t == SCAN_B - 1) bsum[blockIdx.x] = s[t];
}

static __global__ void k_scan2(int* __restrict__ bsum, int nb) {
    __shared__ int s[512];
    int t = threadIdx.x;
    int v = (t < nb) ? bsum[t] : 0;
    s[t] = v;
    __syncthreads();
    for (int off = 1; off < 512; off <<= 1) {
        int x = 0;
        if (t >= off) x = s[t - off];
        __syncthreads();
        if (t >= off) s[t] += x;
        __syncthreads();
    }
    if (t < nb) bsum[t] = s[t] - v;  // exclusive block offsets
}

static __global__ void k_scan3(int* __restrict__ row_off, const int* __restrict__ bsum,
                               int n, int ne) {
    int i = blockIdx.x * SCAN_B + threadIdx.x;
    if (i < n) row_off[i] += bsum[blockIdx.x];
    if (i == 0) row_off[n] = ne;
}

static __global__ void k_copy_i32(const int* __restrict__ a, int* __restrict__ b, int n) {
    int i = blockIdx.x * blockDim.x + threadIdx.x;
    if (i < n) b[i] = a[i];
}

static __global__ void k_fill(const int* __restrict__ src, const int* __restrict__ dst, int ne,
                              int* __restrict__ cursor, int* __restrict__ csr) {
    int e = blockIdx.x * blockDim.x + threadIdx.x;
    if (e < ne) {
        int d = dst[e];
        int p = atomicAdd(&cursor[d], 1);
        csr[p] = src[e];
    }
}

// ---------------- Laplacian gather: out = a*(agg*dinv) + b*Xin + c*Xo ----------------

static __global__ __launch_bounds__(NF) void k_lap(
    const float* __restrict__ Xin, const float* __restrict__ Xo,
    const int* __restrict__ row_off, const int* __restrict__ csr,
    const float* __restrict__ dinv,
    float a, float b, float c,
    float* __restrict__ out, int n) {
    int i = blockIdx.x;
    int t = threadIdx.x;
    int e0 = row_off[i], e1 = row_off[i + 1];
    float acc = 0.f;
    for (int e = e0; e < e1; ++e) {
        int s = csr[e];
        acc += Xin[(size_t)s * NF + t] * dinv[s];
    }
    size_t idx = (size_t)i * NF + t;
    float r = a * (acc * dinv[i]) + b * Xin[idx];
    if (Xo) r += c * Xo[idx];
    out[idx] = r;
}

// ---------------- bf16 MFMA GEMM ----------------
// out[M][N] = concat(X0..X2)[M][Ktot] @ W[N][Ktot]^T  (+epilogue)
// mode 0: y+bias   1: relu(y+bias)   2: bn(relu(y+bias))   3: relu(y+bias)+res
// Tile: BM=128, BN=32*FN (FN=4 -> 128, FN=2 -> 64), BK=32. 4 waves 2x2.
// LDS rows padded to 40 bf16 (80 B) -> 2-way bank aliasing on ds_read_b128 (free).

#define GBM 128
#define GBK 32
#define LDP 40   // padded row stride in bf16 elems

static __device__ inline short f2bf(float f) {
    union { float f; unsigned u; } v; v.f = f;
    unsigned r = v.u + 0x7FFF + ((v.u >> 16) & 1);  // RNE
    return (short)(r >> 16);
}

template <int FN>
static __global__ __launch_bounds__(256) void k_mfma(
    const float* __restrict__ X0, const float* __restrict__ X1, const float* __restrict__ X2,
    int nseg,   // Kseg fixed at 128
    const float* __restrict__ W, const float* __restrict__ bias,
    const float* __restrict__ res,
    const float* __restrict__ bng, const float* __restrict__ bnb,
    const float* __restrict__ bnm, const float* __restrict__ bnv,
    int M, int N, int mode, float* __restrict__ out) {
    constexpr int BN = 32 * FN;            // 2 waves in N, 16*FN each
    __shared__ short As[GBM * LDP];
    __shared__ short Bs[BN * LDP];

    const int t = threadIdx.x;
    const int m0 = blockIdx.x * GBM;
    const int n0 = blockIdx.y * BN;
    const int w  = t >> 6;
    const int wr = w >> 1;         // 0..1 (M)
    const int wc = w & 1;          // 0..1 (N)
    const int l  = t & 63;
    const int lr = l & 15;
    const int lk = l >> 4;

    const int Ktot = 128 * nseg;
    const float* segs[3] = {X0, X1, X2};

    f32x4 acc[4][FN];
#pragma unroll
    for (int i = 0; i < 4; ++i)
#pragma unroll
        for (int j = 0; j < FN; ++j) acc[i][j] = (f32x4){0.f, 0.f, 0.f, 0.f};

    for (int kt = 0; kt < Ktot; kt += GBK) {
        const float* Xp = segs[kt >> 7];
        const int klocal = kt & 127;
        // stage A: 128 rows x 32 k  (1024 float4 -> bf16x4)
#pragma unroll
        for (int it = 0; it < 4; ++it) {
            int idx = it * 256 + t;
            int row = idx >> 3;
            int slot = idx & 7;
            int gm = m0 + row;
            float4 v = make_float4(0.f, 0.f, 0.f, 0.f);
            if (gm < M) v = *(const float4*)&Xp[(size_t)gm * 128 + klocal + slot * 4];
            s16x4 sv; sv.x = f2bf(v.x); sv.y = f2bf(v.y); sv.z = f2bf(v.z); sv.w = f2bf(v.w);
            *(s16x4*)&As[row * LDP + slot * 4] = sv;
        }
        // stage B (W): BN rows x 32 k
#pragma unroll
        for (int it = 0; it < BN / 32; ++it) {
            int idx = it * 256 + t;
            int row = idx >> 3;
            int slot = idx & 7;
            int gn = n0 + row;
            float4 v = *(const float4*)&W[(size_t)gn * Ktot + kt + slot * 4];
            s16x4 sv; sv.x = f2bf(v.x); sv.y = f2bf(v.y); sv.z = f2bf(v.z); sv.w = f2bf(v.w);
            *(s16x4*)&Bs[row * LDP + slot * 4] = sv;
        }
        __syncthreads();

        bf16x8 af[4], bf[FN];
#pragma unroll
        for (int fi = 0; fi < 4; ++fi) {
            int row = wr * 64 + fi * 16 + lr;
            af[fi] = *(const bf16x8*)&As[row * LDP + lk * 8];
        }
#pragma unroll
        for (int fj = 0; fj < FN; ++fj) {
            int row = wc * (16 * FN) + fj * 16 + lr;
            bf[fj] = *(const bf16x8*)&Bs[row * LDP + lk * 8];
        }
#pragma unroll
        for (int fi = 0; fi < 4; ++fi)
#pragma unroll
            for (int fj = 0; fj < FN; ++fj)
                acc[fi][fj] = __builtin_amdgcn_mfma_f32_16x16x32_bf16(af[fi], bf[fj], acc[fi][fj], 0, 0, 0);
        __syncthreads();
    }

    // epilogue: C row = lk*4+reg, col = lr  (m89-verified)
#pragma unroll
    for (int fi = 0; fi < 4; ++fi) {
#pragma unroll
        for (int reg = 0; reg < 4; ++reg) {
            int gm = m0 + wr * 64 + fi * 16 + lk * 4 + reg;
            if (gm >= M) continue;
#pragma unroll
            for (int fj = 0; fj < FN; ++fj) {
                int gn = n0 + wc * (16 * FN) + fj * 16 + lr;
                float y = acc[fi][fj][reg] + bias[gn];
                if (mode >= 1) y = fmaxf(y, 0.f);
                if (mode == 2) {
                    float sc = rsqrtf(bnv[gn] + 1e-5f) * bng[gn];
                    y = (y - bnm[gn]) * sc + bnb[gn];
                }
                if (mode == 3) y += res[(size_t)gm * N + gn];
                out[(size_t)gm * N + gn] = y;
            }
        }
    }
}

// ---------------- launch ----------------

extern "C" void kernel_launch(void* const* d_in, const int* in_sizes, int n_in,
                              void* d_out, int out_size, void* d_ws, size_t ws_size,
                              hipStream_t stream) {
    const float* features = (const float*)d_in[0];
    const int*   esrc     = (const int*)d_in[1];
    const int*   edst     = (const int*)d_in[2];
    const float* W1   = (const float*)d_in[3];
    const float* b1   = (const float*)d_in[4];
    const float* bng  = (const float*)d_in[5];
    const float* bnb  = (const float*)d_in[6];
    const float* bnm  = (const float*)d_in[7];
    const float* bnv  = (const float*)d_in[8];
    const float* W3   = (const float*)d_in[9];
    const float* b3   = (const float*)d_in[10];
    const float* Wm1  = (const float*)d_in[11];
    const float* bm1  = (const float*)d_in[12];
    const float* Wm2  = (const float*)d_in[13];
    const float* bm2  = (const float*)d_in[14];
    float* out = (float*)d_out;

    const int n  = in_sizes[0] / NF;     // 100000
    const int ne = in_sizes[1];          // 600000
    const int OUTF = out_size / n;       // 64

    uint8_t* w = (uint8_t*)d_ws;
    size_t off = 0;
    auto alloc = [&](size_t bytes) -> void* {
        void* p = w + off;
        off = (off + bytes + 255) & ~(size_t)255;
        return p;
    };
    float* dinv   = (float*)alloc((size_t)n * 4);
    int* counts   = (int*)alloc((size_t)n * 4);
    int* row_off  = (int*)alloc(((size_t)n + 1) * 4);
    int* cursor   = (int*)alloc((size_t)n * 4);
    int* csr      = (int*)alloc((size_t)ne * 4);
    int* bsum     = (int*)alloc(4096);
    float* bufB   = (float*)alloc((size_t)n * NF * 4);  // X1
    float* bufC   = (float*)alloc((size_t)n * NF * 4);  // X2
    float* bufD   = (float*)alloc((size_t)n * NF * 4);  // h1 (conv1 out, residual)
    float* bufE   = (float*)alloc((size_t)n * NF * 4);  // conv2 out
    (void)ws_size;

    const int TB = 256;
    const int nbE = (ne + TB - 1) / TB;
    const int nbN = (n + TB - 1) / TB;

    hipMemsetAsync(counts, 0, (size_t)n * 4, stream);
    k_count<<<nbE, TB, 0, stream>>>(edst, ne, counts);
    k_dinv<<<nbN, TB, 0, stream>>>(counts, n, dinv);
    k_scan1<<<nbN, SCAN_B, 0, stream>>>(counts, n, row_off, bsum);
    k_scan2<<<1, 512, 0, stream>>>(bsum, nbN);
    k_scan3<<<nbN, SCAN_B, 0, stream>>>(row_off, bsum, n, ne);
    k_copy_i32<<<nbN, TB, 0, stream>>>(row_off, cursor, n);
    k_fill<<<nbE, TB, 0, stream>>>(esrc, edst, ne, cursor, csr);

    const int gm = (n + GBM - 1) / GBM;

    // ---- conv1 on features ----
    k_lap<<<n, NF, 0, stream>>>(features, nullptr, row_off, csr, dinv, 1.f, -1.f, 0.f, bufB, n);
    k_lap<<<n, NF, 0, stream>>>(bufB, features, row_off, csr, dinv, 2.f, -2.f, -1.f, bufC, n);
    {   // h1 = bn(relu([X0|X1|X2] @ W1^T + b1))
        dim3 g(gm, 1);
        k_mfma<4><<<g, 256, 0, stream>>>(features, bufB, bufC, 3, W1, b1,
                                         nullptr, bng, bnb, bnm, bnv, n, NF, 2, bufD);
    }

    // ---- conv2 on h1 ----
    k_lap<<<n, NF, 0, stream>>>(bufD, nullptr, row_off, csr, dinv, 1.f, -1.f, 0.f, bufB, n);
    k_lap<<<n, NF, 0, stream>>>(bufB, bufD, row_off, csr, dinv, 2.f, -2.f, -1.f, bufC, n);
    {   // x = relu([h1|X1|X2] @ W3^T + b3) + h1
        dim3 g(gm, 1);
        k_mfma<4><<<g, 256, 0, stream>>>(bufD, bufB, bufC, 3, W3, b3,
                                         bufD, nullptr, nullptr, nullptr, nullptr, n, NF, 3, bufE);
    }

    // ---- MLP ----
    {   // h = relu(x @ Wm1^T + bm1)
        dim3 g(gm, 1);
        k_mfma<4><<<g, 256, 0, stream>>>(bufE, nullptr, nullptr, 1, Wm1, bm1,
                                         nullptr, nullptr, nullptr, nullptr, nullptr, n, NF, 1, bufB);
    }
    {   // out = h @ Wm2^T + bm2
        dim3 g(gm, 1);
        k_mfma<2><<<g, 256, 0, stream>>>(bufB, nullptr, nullptr, 1, Wm2, bm2,
                                         nullptr, nullptr, nullptr, nullptr, nullptr, n, OUTF, 0, out);
    }
}

// Round 3
// 501.937 us; speedup vs baseline: 1.9719x; 1.3544x over previous
//
#include <hip/hip_runtime.h>
#include <cstdint>
#include <cstddef>

#define NF 128          // feature width (IN_F == HID_F == 128)
#define SCAN_B 256

typedef __attribute__((ext_vector_type(4))) float f32x4;
typedef __attribute__((ext_vector_type(8))) short bf16x8;
typedef __attribute__((ext_vector_type(4))) short s16x4;

static __device__ inline float bf2f(short u) {
    union { unsigned u; float f; } v;
    v.u = ((unsigned)(unsigned short)u) << 16;
    return v.f;
}
static __device__ inline short f2bf(float f) {
    union { float f; unsigned u; } v; v.f = f;
    unsigned r = v.u + 0x7FFF + ((v.u >> 16) & 1);  // RNE
    return (short)(r >> 16);
}

// ---------------- degree / CSR build ----------------

static __global__ void k_count(const int* __restrict__ dst, int ne, int* __restrict__ counts) {
    int e = blockIdx.x * blockDim.x + threadIdx.x;
    if (e < ne) atomicAdd(&counts[dst[e]], 1);
}

static __global__ void k_dinv(const int* __restrict__ counts, int n, float* __restrict__ dinv) {
    int i = blockIdx.x * blockDim.x + threadIdx.x;
    if (i < n) {
        float d = (float)counts[i];
        d = fmaxf(d, 1.0f);
        dinv[i] = rsqrtf(d);
    }
}

static __global__ void k_scan1(const int* __restrict__ counts, int n,
                               int* __restrict__ row_off, int* __restrict__ bsum) {
    __shared__ int s[SCAN_B];
    int t = threadIdx.x;
    int base = blockIdx.x * SCAN_B;
    int v = (base + t < n) ? counts[base + t] : 0;
    s[t] = v;
    __syncthreads();
    for (int off = 1; off < SCAN_B; off <<= 1) {
        int x = 0;
        if (t >= off) x = s[t - off];
        __syncthreads();
        if (t >= off) s[t] += x;
        __syncthreads();
    }
    if (base + t < n) row_off[base + t] = s[t] - v;
    if (t == SCAN_B - 1) bsum[blockIdx.x] = s[t];
}

static __global__ void k_scan2(int* __restrict__ bsum, int nb) {
    __shared__ int s[512];
    int t = threadIdx.x;
    int v = (t < nb) ? bsum[t] : 0;
    s[t] = v;
    __syncthreads();
    for (int off = 1; off < 512; off <<= 1) {
        int x = 0;
        if (t >= off) x = s[t - off];
        __syncthreads();
        if (t >= off) s[t] += x;
        __syncthreads();
    }
    if (t < nb) bsum[t] = s[t] - v;
}

static __global__ void k_scan3(int* __restrict__ row_off, const int* __restrict__ bsum,
                               int n, int ne) {
    int i = blockIdx.x * SCAN_B + threadIdx.x;
    if (i < n) row_off[i] += bsum[blockIdx.x];
    if (i == 0) row_off[n] = ne;
}

static __global__ void k_copy_i32(const int* __restrict__ a, int* __restrict__ b, int n) {
    int i = blockIdx.x * blockDim.x + threadIdx.x;
    if (i < n) b[i] = a[i];
}

static __global__ void k_fill(const int* __restrict__ src, const int* __restrict__ dst, int ne,
                              int* __restrict__ cursor, int* __restrict__ csr) {
    int e = blockIdx.x * blockDim.x + threadIdx.x;
    if (e < ne) {
        int d = dst[e];
        int p = atomicAdd(&cursor[d], 1);
        csr[p] = src[e];
    }
}

// ---------------- fp32 -> bf16 convert ----------------

static __global__ __launch_bounds__(256) void k_cvt(const float* __restrict__ x,
                                                    short* __restrict__ y, int n8) {
    int i = blockIdx.x * blockDim.x + threadIdx.x;
    if (i < n8) {
        f32x4 a = *(const f32x4*)&x[(size_t)i * 8];
        f32x4 b = *(const f32x4*)&x[(size_t)i * 8 + 4];
        bf16x8 r;
        r[0] = f2bf(a[0]); r[1] = f2bf(a[1]); r[2] = f2bf(a[2]); r[3] = f2bf(a[3]);
        r[4] = f2bf(b[0]); r[5] = f2bf(b[1]); r[6] = f2bf(b[2]); r[7] = f2bf(b[3]);
        *(bf16x8*)&y[(size_t)i * 8] = r;
    }
}

// ---------------- Laplacian gather (bf16 in/out, fp32 accum) ----------------
// out = a*(agg*dinv_i) + b*Xin[i] + c*Xo[i],  agg = sum_src Xin[src]*dinv[src]
// 128 threads per node: 8 edge-groups x 16 lanes; each lane owns an 8-feature slice.

static __global__ __launch_bounds__(128) void k_lap(
    const short* __restrict__ Xin, const short* __restrict__ Xo,
    const int* __restrict__ row_off, const int* __restrict__ csr,
    const float* __restrict__ dinv,
    float a, float b, float c,
    short* __restrict__ out, int n) {
    __shared__ float red[16 * 8];
    int i = blockIdx.x;
    int t = threadIdx.x;
    int g = t >> 4;        // edge group 0..7
    int s = t & 15;        // feature slice (8 elems)
    int e0 = row_off[i], e1 = row_off[i + 1];

    float acc[8];
#pragma unroll
    for (int j = 0; j < 8; ++j) acc[j] = 0.f;

    for (int e = e0 + g; e < e1; e += 8) {
        int src = csr[e];
        float dv = dinv[src];
        bf16x8 v = *(const bf16x8*)&Xin[(size_t)src * NF + s * 8];
#pragma unroll
        for (int j = 0; j < 8; ++j) acc[j] += bf2f(v[j]) * dv;
    }
    // reduce 4 groups within each wave (lane bits 4,5)
#pragma unroll
    for (int j = 0; j < 8; ++j) {
        acc[j] += __shfl_xor(acc[j], 16, 64);
        acc[j] += __shfl_xor(acc[j], 32, 64);
    }
    // cross-wave via LDS
    if (t >= 64 && (t & 63) < 16) {
#pragma unroll
        for (int j = 0; j < 8; ++j) red[s * 8 + j] = acc[j];
    }
    __syncthreads();
    if (t < 16) {
        float di = dinv[i];
        bf16x8 xi = *(const bf16x8*)&Xin[(size_t)i * NF + s * 8];
        bf16x8 r;
        if (Xo) {
            bf16x8 xo = *(const bf16x8*)&Xo[(size_t)i * NF + s * 8];
#pragma unroll
            for (int j = 0; j < 8; ++j) {
                float y = a * ((acc[j] + red[s * 8 + j]) * di) + b * bf2f(xi[j]) + c * bf2f(xo[j]);
                r[j] = f2bf(y);
            }
        } else {
#pragma unroll
            for (int j = 0; j < 8; ++j) {
                float y = a * ((acc[j] + red[s * 8 + j]) * di) + b * bf2f(xi[j]);
                r[j] = f2bf(y);
            }
        }
        *(bf16x8*)&out[(size_t)i * NF + s * 8] = r;
    }
}

// ---------------- bf16 MFMA GEMM ----------------
// out[M][N] = concat(X0..X2)[M][Ktot] @ W[N][Ktot]^T  (+epilogue)
// mode 0: y+bias   1: relu   2: bn(relu)   3: relu + res
// BM=128, BN=32*FN, BK=32, 4 waves 2x2. LDS rows padded to 40 bf16.

#define GBM 128
#define GBK 32
#define LDP 40

template <int FN, bool OBF>
static __global__ __launch_bounds__(256) void k_mfma(
    const short* __restrict__ X0, const short* __restrict__ X1, const short* __restrict__ X2,
    int nseg,   // Kseg fixed at 128
    const float* __restrict__ W, const float* __restrict__ bias,
    const short* __restrict__ res,
    const float* __restrict__ bng, const float* __restrict__ bnb,
    const float* __restrict__ bnm, const float* __restrict__ bnv,
    int M, int N, int mode, void* __restrict__ outv) {
    constexpr int BN = 32 * FN;
    __shared__ short As[GBM * LDP];
    __shared__ short Bs[BN * LDP];

    const int t = threadIdx.x;
    const int m0 = blockIdx.x * GBM;
    const int n0 = blockIdx.y * BN;
    const int w  = t >> 6;
    const int wr = w >> 1;
    const int wc = w & 1;
    const int l  = t & 63;
    const int lr = l & 15;
    const int lk = l >> 4;

    const int Ktot = 128 * nseg;
    const short* segs[3] = {X0, X1, X2};

    f32x4 acc[4][FN];
#pragma unroll
    for (int i = 0; i < 4; ++i)
#pragma unroll
        for (int j = 0; j < FN; ++j) acc[i][j] = (f32x4){0.f, 0.f, 0.f, 0.f};

    for (int kt = 0; kt < Ktot; kt += GBK) {
        const short* Xp = segs[kt >> 7];
        const int klocal = kt & 127;
        // stage A: 128 rows x 32 bf16 (4 x bf16x8 slots per row, 512 tasks)
#pragma unroll
        for (int it = 0; it < 2; ++it) {
            int idx = it * 256 + t;
            int row = idx >> 2;
            int slot = idx & 3;
            int gm = m0 + row;
            bf16x8 v = {0, 0, 0, 0, 0, 0, 0, 0};
            if (gm < M) v = *(const bf16x8*)&Xp[(size_t)gm * 128 + klocal + slot * 8];
            *(bf16x8*)&As[row * LDP + slot * 8] = v;
        }
        // stage B (W, fp32 -> bf16): BN rows x 32 k
#pragma unroll
        for (int it = 0; it < BN / 32; ++it) {
            int idx = it * 256 + t;
            int row = idx >> 3;
            int slot = idx & 7;
            int gn = n0 + row;
            float4 v = *(const float4*)&W[(size_t)gn * Ktot + kt + slot * 4];
            s16x4 sv; sv.x = f2bf(v.x); sv.y = f2bf(v.y); sv.z = f2bf(v.z); sv.w = f2bf(v.w);
            *(s16x4*)&Bs[row * LDP + slot * 4] = sv;
        }
        __syncthreads();

        bf16x8 af[4], bfr[FN];
#pragma unroll
        for (int fi = 0; fi < 4; ++fi) {
            int row = wr * 64 + fi * 16 + lr;
            af[fi] = *(const bf16x8*)&As[row * LDP + lk * 8];
        }
#pragma unroll
        for (int fj = 0; fj < FN; ++fj) {
            int row = wc * (16 * FN) + fj * 16 + lr;
            bfr[fj] = *(const bf16x8*)&Bs[row * LDP + lk * 8];
        }
#pragma unroll
        for (int fi = 0; fi < 4; ++fi)
#pragma unroll
            for (int fj = 0; fj < FN; ++fj)
                acc[fi][fj] = __builtin_amdgcn_mfma_f32_16x16x32_bf16(af[fi], bfr[fj], acc[fi][fj], 0, 0, 0);
        __syncthreads();
    }

    // epilogue: C row = lk*4+reg, col = lr
#pragma unroll
    for (int fi = 0; fi < 4; ++fi) {
#pragma unroll
        for (int reg = 0; reg < 4; ++reg) {
            int gm = m0 + wr * 64 + fi * 16 + lk * 4 + reg;
            if (gm >= M) continue;
#pragma unroll
            for (int fj = 0; fj < FN; ++fj) {
                int gn = n0 + wc * (16 * FN) + fj * 16 + lr;
                float y = acc[fi][fj][reg] + bias[gn];
                if (mode >= 1) y = fmaxf(y, 0.f);
                if (mode == 2) {
                    float sc = rsqrtf(bnv[gn] + 1e-5f) * bng[gn];
                    y = (y - bnm[gn]) * sc + bnb[gn];
                }
                if (mode == 3) y += bf2f(res[(size_t)gm * N + gn]);
                if (OBF) ((short*)outv)[(size_t)gm * N + gn] = f2bf(y);
                else     ((float*)outv)[(size_t)gm * N + gn] = y;
            }
        }
    }
}

// ---------------- launch ----------------

extern "C" void kernel_launch(void* const* d_in, const int* in_sizes, int n_in,
                              void* d_out, int out_size, void* d_ws, size_t ws_size,
                              hipStream_t stream) {
    const float* features = (const float*)d_in[0];
    const int*   esrc     = (const int*)d_in[1];
    const int*   edst     = (const int*)d_in[2];
    const float* W1   = (const float*)d_in[3];
    const float* b1   = (const float*)d_in[4];
    const float* bng  = (const float*)d_in[5];
    const float* bnb  = (const float*)d_in[6];
    const float* bnm  = (const float*)d_in[7];
    const float* bnv  = (const float*)d_in[8];
    const float* W3   = (const float*)d_in[9];
    const float* b3   = (const float*)d_in[10];
    const float* Wm1  = (const float*)d_in[11];
    const float* bm1  = (const float*)d_in[12];
    const float* Wm2  = (const float*)d_in[13];
    const float* bm2  = (const float*)d_in[14];
    float* out = (float*)d_out;

    const int n  = in_sizes[0] / NF;     // 100000
    const int ne = in_sizes[1];          // 600000
    const int OUTF = out_size / n;       // 64

    uint8_t* w = (uint8_t*)d_ws;
    size_t off = 0;
    auto alloc = [&](size_t bytes) -> void* {
        void* p = w + off;
        off = (off + bytes + 255) & ~(size_t)255;
        return p;
    };
    float* dinv   = (float*)alloc((size_t)n * 4);
    int* counts   = (int*)alloc((size_t)n * 4);
    int* row_off  = (int*)alloc(((size_t)n + 1) * 4);
    int* cursor   = (int*)alloc((size_t)n * 4);
    int* csr      = (int*)alloc((size_t)ne * 4);
    int* bsum     = (int*)alloc(4096);
    short* fbf    = (short*)alloc((size_t)n * NF * 2);  // features bf16
    short* bufB   = (short*)alloc((size_t)n * NF * 2);  // X1
    short* bufC   = (short*)alloc((size_t)n * NF * 2);  // X2
    short* bufD   = (short*)alloc((size_t)n * NF * 2);  // h1 (conv1 out, residual)
    short* bufE   = (short*)alloc((size_t)n * NF * 2);  // conv2 out
    (void)ws_size;

    const int TB = 256;
    const int nbE = (ne + TB - 1) / TB;
    const int nbN = (n + TB - 1) / TB;

    hipMemsetAsync(counts, 0, (size_t)n * 4, stream);
    k_count<<<nbE, TB, 0, stream>>>(edst, ne, counts);
    k_dinv<<<nbN, TB, 0, stream>>>(counts, n, dinv);
    k_scan1<<<nbN, SCAN_B, 0, stream>>>(counts, n, row_off, bsum);
    k_scan2<<<1, 512, 0, stream>>>(bsum, nbN);
    k_scan3<<<nbN, SCAN_B, 0, stream>>>(row_off, bsum, n, ne);
    k_copy_i32<<<nbN, TB, 0, stream>>>(row_off, cursor, n);
    k_fill<<<nbE, TB, 0, stream>>>(esrc, edst, ne, cursor, csr);

    // features -> bf16
    {
        int n8 = n * NF / 8;
        k_cvt<<<(n8 + 255) / 256, 256, 0, stream>>>(features, fbf, n8);
    }

    const int gm = (n + GBM - 1) / GBM;

    // ---- conv1 ----
    k_lap<<<n, 128, 0, stream>>>(fbf, nullptr, row_off, csr, dinv, 1.f, -1.f, 0.f, bufB, n);
    k_lap<<<n, 128, 0, stream>>>(bufB, fbf, row_off, csr, dinv, 2.f, -2.f, -1.f, bufC, n);
    {   // h1 = bn(relu([X0|X1|X2] @ W1^T + b1))
        dim3 g(gm, 1);
        k_mfma<4, true><<<g, 256, 0, stream>>>(fbf, bufB, bufC, 3, W1, b1,
                                               nullptr, bng, bnb, bnm, bnv, n, NF, 2, bufD);
    }

    // ---- conv2 ----
    k_lap<<<n, 128, 0, stream>>>(bufD, nullptr, row_off, csr, dinv, 1.f, -1.f, 0.f, bufB, n);
    k_lap<<<n, 128, 0, stream>>>(bufB, bufD, row_off, csr, dinv, 2.f, -2.f, -1.f, bufC, n);
    {   // x = relu([h1|X1|X2] @ W3^T + b3) + h1
        dim3 g(gm, 1);
        k_mfma<4, true><<<g, 256, 0, stream>>>(bufD, bufB, bufC, 3, W3, b3,
                                               bufD, nullptr, nullptr, nullptr, nullptr, n, NF, 3, bufE);
    }

    // ---- MLP ----
    {   // h = relu(x @ Wm1^T + bm1)
        dim3 g(gm, 1);
        k_mfma<4, true><<<g, 256, 0, stream>>>(bufE, nullptr, nullptr, 1, Wm1, bm1,
                                               nullptr, nullptr, nullptr, nullptr, nullptr, n, NF, 1, bufB);
    }
    {   // out = h @ Wm2^T + bm2 (fp32 out)
        dim3 g(gm, 1);
        k_mfma<2, false><<<g, 256, 0, stream>>>(bufB, nullptr, nullptr, 1, Wm2, bm2,
                                                nullptr, nullptr, nullptr, nullptr, nullptr, n, OUTF, 0, out);
    }
}

// Round 4
// 461.735 us; speedup vs baseline: 2.1436x; 1.0871x over previous
//
#include <hip/hip_runtime.h>
#include <cstdint>
#include <cstddef>

#define NF 128          // feature width (IN_F == HID_F == 128)
#define SCAN_B 256

typedef __attribute__((ext_vector_type(4))) float f32x4;
typedef __attribute__((ext_vector_type(8))) short bf16x8;

static __device__ inline float bf2f(short u) {
    union { unsigned u; float f; } v;
    v.u = ((unsigned)(unsigned short)u) << 16;
    return v.f;
}
static __device__ inline short f2bf(float f) {
    union { float f; unsigned u; } v; v.f = f;
    unsigned r = v.u + 0x7FFF + ((v.u >> 16) & 1);  // RNE
    return (short)(r >> 16);
}

// ---------------- degree / CSR build ----------------

static __global__ void k_count(const int* __restrict__ dst, int ne, int* __restrict__ counts) {
    int e = blockIdx.x * blockDim.x + threadIdx.x;
    if (e < ne) atomicAdd(&counts[dst[e]], 1);
}

static __global__ void k_dinv(const int* __restrict__ counts, int n, float* __restrict__ dinv) {
    int i = blockIdx.x * blockDim.x + threadIdx.x;
    if (i < n) {
        float d = (float)counts[i];
        d = fmaxf(d, 1.0f);
        dinv[i] = rsqrtf(d);
    }
}

static __global__ void k_scan1(const int* __restrict__ counts, int n,
                               int* __restrict__ row_off, int* __restrict__ bsum) {
    __shared__ int s[SCAN_B];
    int t = threadIdx.x;
    int base = blockIdx.x * SCAN_B;
    int v = (base + t < n) ? counts[base + t] : 0;
    s[t] = v;
    __syncthreads();
    for (int off = 1; off < SCAN_B; off <<= 1) {
        int x = 0;
        if (t >= off) x = s[t - off];
        __syncthreads();
        if (t >= off) s[t] += x;
        __syncthreads();
    }
    if (base + t < n) row_off[base + t] = s[t] - v;
    if (t == SCAN_B - 1) bsum[blockIdx.x] = s[t];
}

static __global__ void k_scan2(int* __restrict__ bsum, int nb) {
    __shared__ int s[512];
    int t = threadIdx.x;
    int v = (t < nb) ? bsum[t] : 0;
    s[t] = v;
    __syncthreads();
    for (int off = 1; off < 512; off <<= 1) {
        int x = 0;
        if (t >= off) x = s[t - off];
        __syncthreads();
        if (t >= off) s[t] += x;
        __syncthreads();
    }
    if (t < nb) bsum[t] = s[t] - v;
}

static __global__ void k_scan3(int* __restrict__ row_off, const int* __restrict__ bsum,
                               int n, int ne) {
    int i = blockIdx.x * SCAN_B + threadIdx.x;
    if (i < n) row_off[i] += bsum[blockIdx.x];
    if (i == 0) row_off[n] = ne;
}

static __global__ void k_copy_i32(const int* __restrict__ a, int* __restrict__ b, int n) {
    int i = blockIdx.x * blockDim.x + threadIdx.x;
    if (i < n) b[i] = a[i];
}

static __global__ void k_fill(const int* __restrict__ src, const int* __restrict__ dst, int ne,
                              int* __restrict__ cursor, int* __restrict__ csr) {
    int e = blockIdx.x * blockDim.x + threadIdx.x;
    if (e < ne) {
        int d = dst[e];
        int p = atomicAdd(&cursor[d], 1);
        csr[p] = src[e];
    }
}

// ---------------- fp32 -> bf16 convert ----------------

static __global__ __launch_bounds__(256) void k_cvt(const float* __restrict__ x,
                                                    short* __restrict__ y, int n8) {
    int i = blockIdx.x * blockDim.x + threadIdx.x;
    if (i < n8) {
        f32x4 a = *(const f32x4*)&x[(size_t)i * 8];
        f32x4 b = *(const f32x4*)&x[(size_t)i * 8 + 4];
        bf16x8 r;
        r[0] = f2bf(a[0]); r[1] = f2bf(a[1]); r[2] = f2bf(a[2]); r[3] = f2bf(a[3]);
        r[4] = f2bf(b[0]); r[5] = f2bf(b[1]); r[6] = f2bf(b[2]); r[7] = f2bf(b[3]);
        *(bf16x8*)&y[(size_t)i * 8] = r;
    }
}

// ---------------- Laplacian gather (bf16 in/out, fp32 accum) ----------------

static __global__ __launch_bounds__(128) void k_lap(
    const short* __restrict__ Xin, const short* __restrict__ Xo,
    const int* __restrict__ row_off, const int* __restrict__ csr,
    const float* __restrict__ dinv,
    float a, float b, float c,
    short* __restrict__ out, int n) {
    __shared__ float red[16 * 8];
    int i = blockIdx.x;
    int t = threadIdx.x;
    int g = t >> 4;
    int s = t & 15;
    int e0 = row_off[i], e1 = row_off[i + 1];

    float acc[8];
#pragma unroll
    for (int j = 0; j < 8; ++j) acc[j] = 0.f;

    for (int e = e0 + g; e < e1; e += 8) {
        int src = csr[e];
        float dv = dinv[src];
        bf16x8 v = *(const bf16x8*)&Xin[(size_t)src * NF + s * 8];
#pragma unroll
        for (int j = 0; j < 8; ++j) acc[j] += bf2f(v[j]) * dv;
    }
#pragma unroll
    for (int j = 0; j < 8; ++j) {
        acc[j] += __shfl_xor(acc[j], 16, 64);
        acc[j] += __shfl_xor(acc[j], 32, 64);
    }
    if (t >= 64 && (t & 63) < 16) {
#pragma unroll
        for (int j = 0; j < 8; ++j) red[s * 8 + j] = acc[j];
    }
    __syncthreads();
    if (t < 16) {
        float di = dinv[i];
        bf16x8 xi = *(const bf16x8*)&Xin[(size_t)i * NF + s * 8];
        bf16x8 r;
        if (Xo) {
            bf16x8 xo = *(const bf16x8*)&Xo[(size_t)i * NF + s * 8];
#pragma unroll
            for (int j = 0; j < 8; ++j) {
                float y = a * ((acc[j] + red[s * 8 + j]) * di) + b * bf2f(xi[j]) + c * bf2f(xo[j]);
                r[j] = f2bf(y);
            }
        } else {
#pragma unroll
            for (int j = 0; j < 8; ++j) {
                float y = a * ((acc[j] + red[s * 8 + j]) * di) + b * bf2f(xi[j]);
                r[j] = f2bf(y);
            }
        }
        *(bf16x8*)&out[(size_t)i * NF + s * 8] = r;
    }
}

// ---------------- conv GEMM: out[M][128] = concat(X0,X1,X2)[M][384] @ Wbf[128][384]^T ----
// BM=128, BN=64 (grid.y=2), BK=32. 4 waves 2x2, wave tile 64x32 (frag 4x2).
// mode 2: bn(relu(y+b))   mode 3: relu(y+b)+res.  Output bf16.

#define LDP 40

static __global__ __launch_bounds__(256) void k_gemm_conv(
    const short* __restrict__ X0, const short* __restrict__ X1, const short* __restrict__ X2,
    const short* __restrict__ Wbf, const float* __restrict__ bias,
    const short* __restrict__ res,
    const float* __restrict__ bng, const float* __restrict__ bnb,
    const float* __restrict__ bnm, const float* __restrict__ bnv,
    int M, int mode, short* __restrict__ out) {
    __shared__ short As[128 * LDP];
    __shared__ short Bs[64 * LDP];

    const int t = threadIdx.x;
    const int m0 = blockIdx.x * 128;
    const int n0 = blockIdx.y * 64;
    const int w  = t >> 6;
    const int wr = w >> 1;
    const int wc = w & 1;
    const int l  = t & 63;
    const int lr = l & 15;
    const int lk = l >> 4;

    const short* segs[3] = {X0, X1, X2};

    f32x4 acc[4][2];
#pragma unroll
    for (int i = 0; i < 4; ++i)
#pragma unroll
        for (int j = 0; j < 2; ++j) acc[i][j] = (f32x4){0.f, 0.f, 0.f, 0.f};

    for (int kt = 0; kt < 384; kt += 32) {
        const short* Xp = segs[kt >> 7];
        const int klocal = kt & 127;
        // stage A: 128 rows x 4 bf16x8 slots
#pragma unroll
        for (int it = 0; it < 2; ++it) {
            int idx = it * 256 + t;
            int row = idx >> 2;
            int slot = idx & 3;
            int gm = m0 + row;
            bf16x8 v = {0, 0, 0, 0, 0, 0, 0, 0};
            if (gm < M) v = *(const bf16x8*)&Xp[(size_t)gm * 128 + klocal + slot * 8];
            *(bf16x8*)&As[row * LDP + slot * 8] = v;
        }
        // stage B: 64 rows x 4 slots
        {
            int row = t >> 2;
            int slot = t & 3;
            bf16x8 v = *(const bf16x8*)&Wbf[(size_t)(n0 + row) * 384 + kt + slot * 8];
            *(bf16x8*)&Bs[row * LDP + slot * 8] = v;
        }
        __syncthreads();

        bf16x8 af[4], bfr[2];
#pragma unroll
        for (int fi = 0; fi < 4; ++fi)
            af[fi] = *(const bf16x8*)&As[(wr * 64 + fi * 16 + lr) * LDP + lk * 8];
#pragma unroll
        for (int fj = 0; fj < 2; ++fj)
            bfr[fj] = *(const bf16x8*)&Bs[(wc * 32 + fj * 16 + lr) * LDP + lk * 8];
#pragma unroll
        for (int fi = 0; fi < 4; ++fi)
#pragma unroll
            for (int fj = 0; fj < 2; ++fj)
                acc[fi][fj] = __builtin_amdgcn_mfma_f32_16x16x32_bf16(af[fi], bfr[fj], acc[fi][fj], 0, 0, 0);
        __syncthreads();
    }

    // epilogue: C row = lk*4+reg, col = lr
#pragma unroll
    for (int fi = 0; fi < 4; ++fi) {
#pragma unroll
        for (int reg = 0; reg < 4; ++reg) {
            int gm = m0 + wr * 64 + fi * 16 + lk * 4 + reg;
            if (gm >= M) continue;
#pragma unroll
            for (int fj = 0; fj < 2; ++fj) {
                int gn = n0 + wc * 32 + fj * 16 + lr;
                float y = acc[fi][fj][reg] + bias[gn];
                y = fmaxf(y, 0.f);
                if (mode == 2) {
                    float sc = rsqrtf(bnv[gn] + 1e-5f) * bng[gn];
                    y = (y - bnm[gn]) * sc + bnb[gn];
                } else {
                    y += bf2f(res[(size_t)gm * 128 + gn]);
                }
                out[(size_t)gm * 128 + gn] = f2bf(y);
            }
        }
    }
}

// ---------------- fused MLP: out[M][64] = relu(x@Wm1^T+bm1) @ Wm2^T + bm2 ----------------
// BM=64. Phase1: h[64][128] (waves 2x2, wave tile 32x64, frag 2x4) -> LDS.
// Phase2: out[64][64] = h @ Wm2^T (wave tile 32x32, frag 2x2), Wm2 staged per-K-step.

static __global__ __launch_bounds__(256) void k_mlp(
    const short* __restrict__ X, const short* __restrict__ Wm1bf, const float* __restrict__ bm1,
    const short* __restrict__ Wm2bf, const float* __restrict__ bm2,
    int M, float* __restrict__ out) {
    __shared__ short As[64 * LDP];       // phase1 A tile / phase2 B tile
    __shared__ short Bs[128 * LDP];      // phase1 Wm1 tile
    __shared__ short hs[64 * 136];       // h, padded stride 136

    const int t = threadIdx.x;
    const int m0 = blockIdx.x * 64;
    const int w  = t >> 6;
    const int wr = w >> 1;
    const int wc = w & 1;
    const int l  = t & 63;
    const int lr = l & 15;
    const int lk = l >> 4;

    // ---- phase 1: h = relu(X @ Wm1^T + bm1) ----
    f32x4 acc1[2][4];
#pragma unroll
    for (int i = 0; i < 2; ++i)
#pragma unroll
        for (int j = 0; j < 4; ++j) acc1[i][j] = (f32x4){0.f, 0.f, 0.f, 0.f};

    for (int kt = 0; kt < 128; kt += 32) {
        {   // stage A: 64 rows x 4 slots
            int row = t >> 2;
            int slot = t & 3;
            int gm = m0 + row;
            bf16x8 v = {0, 0, 0, 0, 0, 0, 0, 0};
            if (gm < M) v = *(const bf16x8*)&X[(size_t)gm * 128 + kt + slot * 8];
            *(bf16x8*)&As[row * LDP + slot * 8] = v;
        }
        // stage B: 128 rows x 4 slots
#pragma unroll
        for (int it = 0; it < 2; ++it) {
            int idx = it * 256 + t;
            int row = idx >> 2;
            int slot = idx & 3;
            bf16x8 v = *(const bf16x8*)&Wm1bf[(size_t)row * 128 + kt + slot * 8];
            *(bf16x8*)&Bs[row * LDP + slot * 8] = v;
        }
        __syncthreads();

        bf16x8 af[2], bfr[4];
#pragma unroll
        for (int fi = 0; fi < 2; ++fi)
            af[fi] = *(const bf16x8*)&As[(wr * 32 + fi * 16 + lr) * LDP + lk * 8];
#pragma unroll
        for (int fj = 0; fj < 4; ++fj)
            bfr[fj] = *(const bf16x8*)&Bs[(wc * 64 + fj * 16 + lr) * LDP + lk * 8];
#pragma unroll
        for (int fi = 0; fi < 2; ++fi)
#pragma unroll
            for (int fj = 0; fj < 4; ++fj)
                acc1[fi][fj] = __builtin_amdgcn_mfma_f32_16x16x32_bf16(af[fi], bfr[fj], acc1[fi][fj], 0, 0, 0);
        __syncthreads();
    }

    // h -> LDS (relu + bias), C row = lk*4+reg, col = lr
#pragma unroll
    for (int fi = 0; fi < 2; ++fi) {
#pragma unroll
        for (int reg = 0; reg < 4; ++reg) {
            int rloc = wr * 32 + fi * 16 + lk * 4 + reg;
#pragma unroll
            for (int fj = 0; fj < 4; ++fj) {
                int col = wc * 64 + fj * 16 + lr;
                float y = acc1[fi][fj][reg] + bm1[col];
                hs[rloc * 136 + col] = f2bf(fmaxf(y, 0.f));
            }
        }
    }
    __syncthreads();

    // ---- phase 2: out = h @ Wm2^T + bm2 ----
    f32x4 acc2[2][2];
#pragma unroll
    for (int i = 0; i < 2; ++i)
#pragma unroll
        for (int j = 0; j < 2; ++j) acc2[i][j] = (f32x4){0.f, 0.f, 0.f, 0.f};

    for (int kt = 0; kt < 128; kt += 32) {
        {   // stage Wm2 tile into As: 64 rows x 4 slots
            int row = t >> 2;
            int slot = t & 3;
            bf16x8 v = *(const bf16x8*)&Wm2bf[(size_t)row * 128 + kt + slot * 8];
            *(bf16x8*)&As[row * LDP + slot * 8] = v;
        }
        __syncthreads();

        bf16x8 af[2], bfr[2];
#pragma unroll
        for (int fi = 0; fi < 2; ++fi)
            af[fi] = *(const bf16x8*)&hs[(wr * 32 + fi * 16 + lr) * 136 + kt + lk * 8];
#pragma unroll
        for (int fj = 0; fj < 2; ++fj)
            bfr[fj] = *(const bf16x8*)&As[(wc * 32 + fj * 16 + lr) * LDP + lk * 8];
#pragma unroll
        for (int fi = 0; fi < 2; ++fi)
#pragma unroll
            for (int fj = 0; fj < 2; ++fj)
                acc2[fi][fj] = __builtin_amdgcn_mfma_f32_16x16x32_bf16(af[fi], bfr[fj], acc2[fi][fj], 0, 0, 0);
        __syncthreads();
    }

#pragma unroll
    for (int fi = 0; fi < 2; ++fi) {
#pragma unroll
        for (int reg = 0; reg < 4; ++reg) {
            int gm = m0 + wr * 32 + fi * 16 + lk * 4 + reg;
            if (gm >= M) continue;
#pragma unroll
            for (int fj = 0; fj < 2; ++fj) {
                int gn = wc * 32 + fj * 16 + lr;
                out[(size_t)gm * 64 + gn] = acc2[fi][fj][reg] + bm2[gn];
            }
        }
    }
}

// ---------------- launch ----------------

extern "C" void kernel_launch(void* const* d_in, const int* in_sizes, int n_in,
                              void* d_out, int out_size, void* d_ws, size_t ws_size,
                              hipStream_t stream) {
    const float* features = (const float*)d_in[0];
    const int*   esrc     = (const int*)d_in[1];
    const int*   edst     = (const int*)d_in[2];
    const float* W1   = (const float*)d_in[3];
    const float* b1   = (const float*)d_in[4];
    const float* bng  = (const float*)d_in[5];
    const float* bnb  = (const float*)d_in[6];
    const float* bnm  = (const float*)d_in[7];
    const float* bnv  = (const float*)d_in[8];
    const float* W3   = (const float*)d_in[9];
    const float* b3   = (const float*)d_in[10];
    const float* Wm1  = (const float*)d_in[11];
    const float* bm1  = (const float*)d_in[12];
    const float* Wm2  = (const float*)d_in[13];
    const float* bm2  = (const float*)d_in[14];
    float* out = (float*)d_out;

    const int n  = in_sizes[0] / NF;     // 100000
    const int ne = in_sizes[1];          // 600000

    uint8_t* w = (uint8_t*)d_ws;
    size_t off = 0;
    auto alloc = [&](size_t bytes) -> void* {
        void* p = w + off;
        off = (off + bytes + 255) & ~(size_t)255;
        return p;
    };
    float* dinv   = (float*)alloc((size_t)n * 4);
    int* counts   = (int*)alloc((size_t)n * 4);
    int* row_off  = (int*)alloc(((size_t)n + 1) * 4);
    int* cursor   = (int*)alloc((size_t)n * 4);
    int* csr      = (int*)alloc((size_t)ne * 4);
    int* bsum     = (int*)alloc(4096);
    short* fbf    = (short*)alloc((size_t)n * NF * 2);
    short* bufB   = (short*)alloc((size_t)n * NF * 2);
    short* bufC   = (short*)alloc((size_t)n * NF * 2);
    short* bufD   = (short*)alloc((size_t)n * NF * 2);
    short* bufE   = (short*)alloc((size_t)n * NF * 2);
    short* W1bf   = (short*)alloc((size_t)128 * 384 * 2);
    short* W3bf   = (short*)alloc((size_t)128 * 384 * 2);
    short* Wm1bf  = (short*)alloc((size_t)128 * 128 * 2);
    short* Wm2bf  = (short*)alloc((size_t)64 * 128 * 2);
    (void)ws_size;

    const int TB = 256;
    const int nbE = (ne + TB - 1) / TB;
    const int nbN = (n + TB - 1) / TB;

    hipMemsetAsync(counts, 0, (size_t)n * 4, stream);
    k_count<<<nbE, TB, 0, stream>>>(edst, ne, counts);
    k_dinv<<<nbN, TB, 0, stream>>>(counts, n, dinv);
    k_scan1<<<nbN, SCAN_B, 0, stream>>>(counts, n, row_off, bsum);
    k_scan2<<<1, 512, 0, stream>>>(bsum, nbN);
    k_scan3<<<nbN, SCAN_B, 0, stream>>>(row_off, bsum, n, ne);
    k_copy_i32<<<nbN, TB, 0, stream>>>(row_off, cursor, n);
    k_fill<<<nbE, TB, 0, stream>>>(esrc, edst, ne, cursor, csr);

    // converts
    {
        int n8 = n * NF / 8;
        k_cvt<<<(n8 + 255) / 256, 256, 0, stream>>>(features, fbf, n8);
        k_cvt<<<(6144 + 255) / 256, 256, 0, stream>>>(W1, W1bf, 6144);
        k_cvt<<<(6144 + 255) / 256, 256, 0, stream>>>(W3, W3bf, 6144);
        k_cvt<<<(2048 + 255) / 256, 256, 0, stream>>>(Wm1, Wm1bf, 2048);
        k_cvt<<<(1024 + 255) / 256, 256, 0, stream>>>(Wm2, Wm2bf, 1024);
    }

    const int gm128 = (n + 127) / 128;
    const int gm64  = (n + 63) / 64;

    // ---- conv1 ----
    k_lap<<<n, 128, 0, stream>>>(fbf, nullptr, row_off, csr, dinv, 1.f, -1.f, 0.f, bufB, n);
    k_lap<<<n, 128, 0, stream>>>(bufB, fbf, row_off, csr, dinv, 2.f, -2.f, -1.f, bufC, n);
    {
        dim3 g(gm128, 2);
        k_gemm_conv<<<g, 256, 0, stream>>>(fbf, bufB, bufC, W1bf, b1,
                                           nullptr, bng, bnb, bnm, bnv, n, 2, bufD);
    }

    // ---- conv2 ----
    k_lap<<<n, 128, 0, stream>>>(bufD, nullptr, row_off, csr, dinv, 1.f, -1.f, 0.f, bufB, n);
    k_lap<<<n, 128, 0, stream>>>(bufB, bufD, row_off, csr, dinv, 2.f, -2.f, -1.f, bufC, n);
    {
        dim3 g(gm128, 2);
        k_gemm_conv<<<g, 256, 0, stream>>>(bufD, bufB, bufC, W3bf, b3,
                                           bufD, nullptr, nullptr, nullptr, nullptr, n, 3, bufE);
    }

    // ---- fused MLP ----
    k_mlp<<<gm64, 256, 0, stream>>>(bufE, Wm1bf, bm1, Wm2bf, bm2, n, out);
}

// Round 5
// 440.748 us; speedup vs baseline: 2.2457x; 1.0476x over previous
//
#include <hip/hip_runtime.h>
#include <cstdint>
#include <cstddef>

#define NF 128          // feature width (IN_F == HID_F == 128)
#define SCAN_B 256

typedef __attribute__((ext_vector_type(4))) float f32x4;
typedef __attribute__((ext_vector_type(8))) short bf16x8;

static __device__ inline float bf2f(short u) {
    union { unsigned u; float f; } v;
    v.u = ((unsigned)(unsigned short)u) << 16;
    return v.f;
}
static __device__ inline short f2bf(float f) {
    union { float f; unsigned u; } v; v.f = f;
    unsigned r = v.u + 0x7FFF + ((v.u >> 16) & 1);  // RNE
    return (short)(r >> 16);
}
static __device__ inline float u2f(unsigned u) {
    union { unsigned u; float f; } v; v.u = u; return v.f;
}
static __device__ inline unsigned f2u(float f) {
    union { float f; unsigned u; } v; v.f = f; return v.u;
}
// pack two f32 -> bf16x2 in u32 (RNE)
static __device__ inline unsigned packbf(float lo, float hi) {
    unsigned ul = f2u(lo), uh = f2u(hi);
    ul = ul + 0x7FFF + ((ul >> 16) & 1);
    uh = uh + 0x7FFF + ((uh >> 16) & 1);
    return (ul >> 16) | (uh & 0xFFFF0000u);
}

// ---------------- degree / CSR build ----------------

static __global__ void k_count(const int* __restrict__ dst, int ne, int* __restrict__ counts) {
    int e = blockIdx.x * blockDim.x + threadIdx.x;
    if (e < ne) atomicAdd(&counts[dst[e]], 1);
}

static __global__ void k_dinv(const int* __restrict__ counts, int n, float* __restrict__ dinv) {
    int i = blockIdx.x * blockDim.x + threadIdx.x;
    if (i < n) {
        float d = (float)counts[i];
        d = fmaxf(d, 1.0f);
        dinv[i] = rsqrtf(d);
    }
}

static __global__ void k_scan1(const int* __restrict__ counts, int n,
                               int* __restrict__ row_off, int* __restrict__ bsum) {
    __shared__ int s[SCAN_B];
    int t = threadIdx.x;
    int base = blockIdx.x * SCAN_B;
    int v = (base + t < n) ? counts[base + t] : 0;
    s[t] = v;
    __syncthreads();
    for (int off = 1; off < SCAN_B; off <<= 1) {
        int x = 0;
        if (t >= off) x = s[t - off];
        __syncthreads();
        if (t >= off) s[t] += x;
        __syncthreads();
    }
    if (base + t < n) row_off[base + t] = s[t] - v;
    if (t == SCAN_B - 1) bsum[blockIdx.x] = s[t];
}

static __global__ void k_scan2(int* __restrict__ bsum, int nb) {
    __shared__ int s[512];
    int t = threadIdx.x;
    int v = (t < nb) ? bsum[t] : 0;
    s[t] = v;
    __syncthreads();
    for (int off = 1; off < 512; off <<= 1) {
        int x = 0;
        if (t >= off) x = s[t - off];
        __syncthreads();
        if (t >= off) s[t] += x;
        __syncthreads();
    }
    if (t < nb) bsum[t] = s[t] - v;
}

static __global__ void k_scan3(int* __restrict__ row_off, const int* __restrict__ bsum,
                               int n, int ne) {
    int i = blockIdx.x * SCAN_B + threadIdx.x;
    if (i < n) row_off[i] += bsum[blockIdx.x];
    if (i == 0) row_off[n] = ne;
}

static __global__ void k_copy_i32(const int* __restrict__ a, int* __restrict__ b, int n) {
    int i = blockIdx.x * blockDim.x + threadIdx.x;
    if (i < n) b[i] = a[i];
}

static __global__ void k_fill(const int* __restrict__ src, const int* __restrict__ dst, int ne,
                              int* __restrict__ cursor, int* __restrict__ csr) {
    int e = blockIdx.x * blockDim.x + threadIdx.x;
    if (e < ne) {
        int d = dst[e];
        int p = atomicAdd(&cursor[d], 1);
        csr[p] = src[e];
    }
}

// ---------------- fp32 -> bf16 convert ----------------

static __global__ __launch_bounds__(256) void k_cvt(const float* __restrict__ x,
                                                    short* __restrict__ y, int n8) {
    int i = blockIdx.x * blockDim.x + threadIdx.x;
    if (i < n8) {
        f32x4 a = *(const f32x4*)&x[(size_t)i * 8];
        f32x4 b = *(const f32x4*)&x[(size_t)i * 8 + 4];
        bf16x8 r;
        r[0] = f2bf(a[0]); r[1] = f2bf(a[1]); r[2] = f2bf(a[2]); r[3] = f2bf(a[3]);
        r[4] = f2bf(b[0]); r[5] = f2bf(b[1]); r[6] = f2bf(b[2]); r[7] = f2bf(b[3]);
        *(bf16x8*)&y[(size_t)i * 8] = r;
    }
}

// ---------------- Laplacian gather: one wave per node ----------------
// out = a*(agg*dinv_i) + b*Xin[i] + c*Xo[i],  agg = sum_src Xin[src]*dinv[src]
// 64 lanes x 1 u32 (2 bf16) = full 128-feature row. Edge loop is wave-uniform;
// no shuffles / LDS / syncthreads. 4 nodes per 256-thread block.

static __global__ __launch_bounds__(256) void k_lap(
    const short* __restrict__ Xin, const short* __restrict__ Xo,
    const int* __restrict__ row_off, const int* __restrict__ csr,
    const float* __restrict__ dinv,
    float a, float b, float c,
    short* __restrict__ out, int n) {
    int node = blockIdx.x * 4 + (threadIdx.x >> 6);
    if (node >= n) return;
    int l = threadIdx.x & 63;
    const unsigned* Xu = (const unsigned*)Xin;
    int e0 = row_off[node], e1 = row_off[node + 1];

    float a0 = 0.f, a1 = 0.f, b0 = 0.f, b1 = 0.f;
    int e = e0;
    for (; e + 1 < e1; e += 2) {
        int s0 = csr[e], s1 = csr[e + 1];
        float d0 = dinv[s0], d1 = dinv[s1];
        unsigned v0 = Xu[(size_t)s0 * 64 + l];
        unsigned v1 = Xu[(size_t)s1 * 64 + l];
        a0 += u2f(v0 << 16) * d0;
        a1 += u2f(v0 & 0xFFFF0000u) * d0;
        b0 += u2f(v1 << 16) * d1;
        b1 += u2f(v1 & 0xFFFF0000u) * d1;
    }
    if (e < e1) {
        int s0 = csr[e];
        float d0 = dinv[s0];
        unsigned v0 = Xu[(size_t)s0 * 64 + l];
        a0 += u2f(v0 << 16) * d0;
        a1 += u2f(v0 & 0xFFFF0000u) * d0;
    }
    a0 += b0; a1 += b1;

    float di = dinv[node];
    unsigned xi = Xu[(size_t)node * 64 + l];
    float y0 = a * (a0 * di) + b * u2f(xi << 16);
    float y1 = a * (a1 * di) + b * u2f(xi & 0xFFFF0000u);
    if (Xo) {
        unsigned xo = ((const unsigned*)Xo)[(size_t)node * 64 + l];
        y0 += c * u2f(xo << 16);
        y1 += c * u2f(xo & 0xFFFF0000u);
    }
    ((unsigned*)out)[(size_t)node * 64 + l] = packbf(y0, y1);
}

// ---------------- conv GEMM: out[M][128] = concat(X0,X1,X2)[M][384] @ Wbf[128][384]^T ----
// BM=128, BN=64 (grid.y=2), BK=32. 4 waves 2x2, wave tile 64x32 (frag 4x2).
// mode 2: bn(relu(y+b))   mode 3: relu(y+b)+res.  Output bf16.

#define LDP 40

static __global__ __launch_bounds__(256) void k_gemm_conv(
    const short* __restrict__ X0, const short* __restrict__ X1, const short* __restrict__ X2,
    const short* __restrict__ Wbf, const float* __restrict__ bias,
    const short* __restrict__ res,
    const float* __restrict__ bng, const float* __restrict__ bnb,
    const float* __restrict__ bnm, const float* __restrict__ bnv,
    int M, int mode, short* __restrict__ out) {
    __shared__ short As[128 * LDP];
    __shared__ short Bs[64 * LDP];

    const int t = threadIdx.x;
    const int m0 = blockIdx.x * 128;
    const int n0 = blockIdx.y * 64;
    const int w  = t >> 6;
    const int wr = w >> 1;
    const int wc = w & 1;
    const int l  = t & 63;
    const int lr = l & 15;
    const int lk = l >> 4;

    const short* segs[3] = {X0, X1, X2};

    f32x4 acc[4][2];
#pragma unroll
    for (int i = 0; i < 4; ++i)
#pragma unroll
        for (int j = 0; j < 2; ++j) acc[i][j] = (f32x4){0.f, 0.f, 0.f, 0.f};

    for (int kt = 0; kt < 384; kt += 32) {
        const short* Xp = segs[kt >> 7];
        const int klocal = kt & 127;
#pragma unroll
        for (int it = 0; it < 2; ++it) {
            int idx = it * 256 + t;
            int row = idx >> 2;
            int slot = idx & 3;
            int gm = m0 + row;
            bf16x8 v = {0, 0, 0, 0, 0, 0, 0, 0};
            if (gm < M) v = *(const bf16x8*)&Xp[(size_t)gm * 128 + klocal + slot * 8];
            *(bf16x8*)&As[row * LDP + slot * 8] = v;
        }
        {
            int row = t >> 2;
            int slot = t & 3;
            bf16x8 v = *(const bf16x8*)&Wbf[(size_t)(n0 + row) * 384 + kt + slot * 8];
            *(bf16x8*)&Bs[row * LDP + slot * 8] = v;
        }
        __syncthreads();

        bf16x8 af[4], bfr[2];
#pragma unroll
        for (int fi = 0; fi < 4; ++fi)
            af[fi] = *(const bf16x8*)&As[(wr * 64 + fi * 16 + lr) * LDP + lk * 8];
#pragma unroll
        for (int fj = 0; fj < 2; ++fj)
            bfr[fj] = *(const bf16x8*)&Bs[(wc * 32 + fj * 16 + lr) * LDP + lk * 8];
#pragma unroll
        for (int fi = 0; fi < 4; ++fi)
#pragma unroll
            for (int fj = 0; fj < 2; ++fj)
                acc[fi][fj] = __builtin_amdgcn_mfma_f32_16x16x32_bf16(af[fi], bfr[fj], acc[fi][fj], 0, 0, 0);
        __syncthreads();
    }

    // epilogue: C row = lk*4+reg, col = lr
#pragma unroll
    for (int fi = 0; fi < 4; ++fi) {
#pragma unroll
        for (int reg = 0; reg < 4; ++reg) {
            int gm = m0 + wr * 64 + fi * 16 + lk * 4 + reg;
            if (gm >= M) continue;
#pragma unroll
            for (int fj = 0; fj < 2; ++fj) {
                int gn = n0 + wc * 32 + fj * 16 + lr;
                float y = acc[fi][fj][reg] + bias[gn];
                y = fmaxf(y, 0.f);
                if (mode == 2) {
                    float sc = rsqrtf(bnv[gn] + 1e-5f) * bng[gn];
                    y = (y - bnm[gn]) * sc + bnb[gn];
                } else {
                    y += bf2f(res[(size_t)gm * 128 + gn]);
                }
                out[(size_t)gm * 128 + gn] = f2bf(y);
            }
        }
    }
}

// ---------------- fused MLP: out[M][64] = relu(x@Wm1^T+bm1) @ Wm2^T + bm2 ----------------

static __global__ __launch_bounds__(256) void k_mlp(
    const short* __restrict__ X, const short* __restrict__ Wm1bf, const float* __restrict__ bm1,
    const short* __restrict__ Wm2bf, const float* __restrict__ bm2,
    int M, float* __restrict__ out) {
    __shared__ short As[64 * LDP];       // phase1 A tile / phase2 B tile
    __shared__ short Bs[128 * LDP];      // phase1 Wm1 tile
    __shared__ short hs[64 * 136];       // h, padded stride 136

    const int t = threadIdx.x;
    const int m0 = blockIdx.x * 64;
    const int w  = t >> 6;
    const int wr = w >> 1;
    const int wc = w & 1;
    const int l  = t & 63;
    const int lr = l & 15;
    const int lk = l >> 4;

    f32x4 acc1[2][4];
#pragma unroll
    for (int i = 0; i < 2; ++i)
#pragma unroll
        for (int j = 0; j < 4; ++j) acc1[i][j] = (f32x4){0.f, 0.f, 0.f, 0.f};

    for (int kt = 0; kt < 128; kt += 32) {
        {
            int row = t >> 2;
            int slot = t & 3;
            int gm = m0 + row;
            bf16x8 v = {0, 0, 0, 0, 0, 0, 0, 0};
            if (gm < M) v = *(const bf16x8*)&X[(size_t)gm * 128 + kt + slot * 8];
            *(bf16x8*)&As[row * LDP + slot * 8] = v;
        }
#pragma unroll
        for (int it = 0; it < 2; ++it) {
            int idx = it * 256 + t;
            int row = idx >> 2;
            int slot = idx & 3;
            bf16x8 v = *(const bf16x8*)&Wm1bf[(size_t)row * 128 + kt + slot * 8];
            *(bf16x8*)&Bs[row * LDP + slot * 8] = v;
        }
        __syncthreads();

        bf16x8 af[2], bfr[4];
#pragma unroll
        for (int fi = 0; fi < 2; ++fi)
            af[fi] = *(const bf16x8*)&As[(wr * 32 + fi * 16 + lr) * LDP + lk * 8];
#pragma unroll
        for (int fj = 0; fj < 4; ++fj)
            bfr[fj] = *(const bf16x8*)&Bs[(wc * 64 + fj * 16 + lr) * LDP + lk * 8];
#pragma unroll
        for (int fi = 0; fi < 2; ++fi)
#pragma unroll
            for (int fj = 0; fj < 4; ++fj)
                acc1[fi][fj] = __builtin_amdgcn_mfma_f32_16x16x32_bf16(af[fi], bfr[fj], acc1[fi][fj], 0, 0, 0);
        __syncthreads();
    }

#pragma unroll
    for (int fi = 0; fi < 2; ++fi) {
#pragma unroll
        for (int reg = 0; reg < 4; ++reg) {
            int rloc = wr * 32 + fi * 16 + lk * 4 + reg;
#pragma unroll
            for (int fj = 0; fj < 4; ++fj) {
                int col = wc * 64 + fj * 16 + lr;
                float y = acc1[fi][fj][reg] + bm1[col];
                hs[rloc * 136 + col] = f2bf(fmaxf(y, 0.f));
            }
        }
    }
    __syncthreads();

    f32x4 acc2[2][2];
#pragma unroll
    for (int i = 0; i < 2; ++i)
#pragma unroll
        for (int j = 0; j < 2; ++j) acc2[i][j] = (f32x4){0.f, 0.f, 0.f, 0.f};

    for (int kt = 0; kt < 128; kt += 32) {
        {
            int row = t >> 2;
            int slot = t & 3;
            bf16x8 v = *(const bf16x8*)&Wm2bf[(size_t)row * 128 + kt + slot * 8];
            *(bf16x8*)&As[row * LDP + slot * 8] = v;
        }
        __syncthreads();

        bf16x8 af[2], bfr[2];
#pragma unroll
        for (int fi = 0; fi < 2; ++fi)
            af[fi] = *(const bf16x8*)&hs[(wr * 32 + fi * 16 + lr) * 136 + kt + lk * 8];
#pragma unroll
        for (int fj = 0; fj < 2; ++fj)
            bfr[fj] = *(const bf16x8*)&As[(wc * 32 + fj * 16 + lr) * LDP + lk * 8];
#pragma unroll
        for (int fi = 0; fi < 2; ++fi)
#pragma unroll
            for (int fj = 0; fj < 2; ++fj)
                acc2[fi][fj] = __builtin_amdgcn_mfma_f32_16x16x32_bf16(af[fi], bfr[fj], acc2[fi][fj], 0, 0, 0);
        __syncthreads();
    }

#pragma unroll
    for (int fi = 0; fi < 2; ++fi) {
#pragma unroll
        for (int reg = 0; reg < 4; ++reg) {
            int gm = m0 + wr * 32 + fi * 16 + lk * 4 + reg;
            if (gm >= M) continue;
#pragma unroll
            for (int fj = 0; fj < 2; ++fj) {
                int gn = wc * 32 + fj * 16 + lr;
                out[(size_t)gm * 64 + gn] = acc2[fi][fj][reg] + bm2[gn];
            }
        }
    }
}

// ---------------- launch ----------------

extern "C" void kernel_launch(void* const* d_in, const int* in_sizes, int n_in,
                              void* d_out, int out_size, void* d_ws, size_t ws_size,
                              hipStream_t stream) {
    const float* features = (const float*)d_in[0];
    const int*   esrc     = (const int*)d_in[1];
    const int*   edst     = (const int*)d_in[2];
    const float* W1   = (const float*)d_in[3];
    const float* b1   = (const float*)d_in[4];
    const float* bng  = (const float*)d_in[5];
    const float* bnb  = (const float*)d_in[6];
    const float* bnm  = (const float*)d_in[7];
    const float* bnv  = (const float*)d_in[8];
    const float* W3   = (const float*)d_in[9];
    const float* b3   = (const float*)d_in[10];
    const float* Wm1  = (const float*)d_in[11];
    const float* bm1  = (const float*)d_in[12];
    const float* Wm2  = (const float*)d_in[13];
    const float* bm2  = (const float*)d_in[14];
    float* out = (float*)d_out;

    const int n  = in_sizes[0] / NF;     // 100000
    const int ne = in_sizes[1];          // 600000

    uint8_t* w = (uint8_t*)d_ws;
    size_t off = 0;
    auto alloc = [&](size_t bytes) -> void* {
        void* p = w + off;
        off = (off + bytes + 255) & ~(size_t)255;
        return p;
    };
    float* dinv   = (float*)alloc((size_t)n * 4);
    int* counts   = (int*)alloc((size_t)n * 4);
    int* row_off  = (int*)alloc(((size_t)n + 1) * 4);
    int* cursor   = (int*)alloc((size_t)n * 4);
    int* csr      = (int*)alloc((size_t)ne * 4);
    int* bsum     = (int*)alloc(4096);
    short* fbf    = (short*)alloc((size_t)n * NF * 2);
    short* bufB   = (short*)alloc((size_t)n * NF * 2);
    short* bufC   = (short*)alloc((size_t)n * NF * 2);
    short* bufD   = (short*)alloc((size_t)n * NF * 2);
    short* bufE   = (short*)alloc((size_t)n * NF * 2);
    short* W1bf   = (short*)alloc((size_t)128 * 384 * 2);
    short* W3bf   = (short*)alloc((size_t)128 * 384 * 2);
    short* Wm1bf  = (short*)alloc((size_t)128 * 128 * 2);
    short* Wm2bf  = (short*)alloc((size_t)64 * 128 * 2);
    (void)ws_size;

    const int TB = 256;
    const int nbE = (ne + TB - 1) / TB;
    const int nbN = (n + TB - 1) / TB;

    hipMemsetAsync(counts, 0, (size_t)n * 4, stream);
    k_count<<<nbE, TB, 0, stream>>>(edst, ne, counts);
    k_dinv<<<nbN, TB, 0, stream>>>(counts, n, dinv);
    k_scan1<<<nbN, SCAN_B, 0, stream>>>(counts, n, row_off, bsum);
    k_scan2<<<1, 512, 0, stream>>>(bsum, nbN);
    k_scan3<<<nbN, SCAN_B, 0, stream>>>(row_off, bsum, n, ne);
    k_copy_i32<<<nbN, TB, 0, stream>>>(row_off, cursor, n);
    k_fill<<<nbE, TB, 0, stream>>>(esrc, edst, ne, cursor, csr);

    {
        int n8 = n * NF / 8;
        k_cvt<<<(n8 + 255) / 256, 256, 0, stream>>>(features, fbf, n8);
        k_cvt<<<(6144 + 255) / 256, 256, 0, stream>>>(W1, W1bf, 6144);
        k_cvt<<<(6144 + 255) / 256, 256, 0, stream>>>(W3, W3bf, 6144);
        k_cvt<<<(2048 + 255) / 256, 256, 0, stream>>>(Wm1, Wm1bf, 2048);
        k_cvt<<<(1024 + 255) / 256, 256, 0, stream>>>(Wm2, Wm2bf, 1024);
    }

    const int gm128 = (n + 127) / 128;
    const int gm64  = (n + 63) / 64;
    const int nbL   = (n + 3) / 4;   // lap: 4 nodes per 256-thread block

    // ---- conv1 ----
    k_lap<<<nbL, 256, 0, stream>>>(fbf, nullptr, row_off, csr, dinv, 1.f, -1.f, 0.f, bufB, n);
    k_lap<<<nbL, 256, 0, stream>>>(bufB, fbf, row_off, csr, dinv, 2.f, -2.f, -1.f, bufC, n);
    {
        dim3 g(gm128, 2);
        k_gemm_conv<<<g, 256, 0, stream>>>(fbf, bufB, bufC, W1bf, b1,
                                           nullptr, bng, bnb, bnm, bnv, n, 2, bufD);
    }

    // ---- conv2 ----
    k_lap<<<nbL, 256, 0, stream>>>(bufD, nullptr, row_off, csr, dinv, 1.f, -1.f, 0.f, bufB, n);
    k_lap<<<nbL, 256, 0, stream>>>(bufB, bufD, row_off, csr, dinv, 2.f, -2.f, -1.f, bufC, n);
    {
        dim3 g(gm128, 2);
        k_gemm_conv<<<g, 256, 0, stream>>>(bufD, bufB, bufC, W3bf, b3,
                                           bufD, nullptr, nullptr, nullptr, nullptr, n, 3, bufE);
    }

    // ---- fused MLP ----
    k_mlp<<<gm64, 256, 0, stream>>>(bufE, Wm1bf, bm1, Wm2bf, bm2, n, out);
}